// Round 1
// baseline (433.920 us; speedup 1.0000x reference)
//
#include <hip/hip_runtime.h>

#define N_NODES 100000
#define N_EDGES 1000000
#define D 64

// Phase 1a: scatter-add features. One thread per (edge, dim).
// 64 consecutive threads = one edge -> coalesced 256B read of feat row,
// coalesced (but atomic) 256B add into accum row.
__global__ void scatter_feat(const float* __restrict__ feat,
                             const int* __restrict__ src,
                             const int* __restrict__ dst,
                             float* __restrict__ accum) {
    long long idx = (long long)blockIdx.x * blockDim.x + threadIdx.x;
    if (idx >= (long long)N_EDGES * D) return;
    int e = (int)(idx >> 6);
    int d = (int)(idx & 63);
    int s = src[e];
    int t = dst[e];
    float v = feat[s * D + d];
    atomicAdd(accum + t * D + d, v);
}

// Phase 1b: degree counts.
__global__ void scatter_deg(const int* __restrict__ dst,
                            float* __restrict__ deg) {
    int e = blockIdx.x * blockDim.x + threadIdx.x;
    if (e >= N_EDGES) return;
    atomicAdd(deg + dst[e], 1.0f);
}

// Phase 2: per-node mean + type-routed 64x64 linear, in place over `out`.
// One wave (64 lanes) per node; lane = output dim. Each lane reads one
// element of the accumulated row (register), then shuffles to broadcast.
// In-place is safe: all reads of the row happen before the write, and rows
// are wave-private.
__global__ void apply_linear(const float* __restrict__ gate_W,
                             const float* __restrict__ gate_b,
                             const int* __restrict__ ntype2,
                             const float* __restrict__ deg,
                             float* __restrict__ out) {
    int node = blockIdx.x * (blockDim.x >> 6) + (threadIdx.x >> 6);
    int lane = threadIdx.x & 63;
    if (node >= N_NODES) return;

    int t = ntype2[node];
    float dv = deg[node];
    dv = dv > 1.0f ? dv : 1.0f;
    float nv = out[node * D + lane] / dv;   // this lane's element of neigh-mean

    const float* __restrict__ W = gate_W + t * D * D;
    float acc = gate_b[t * D + lane];
#pragma unroll 16
    for (int d = 0; d < D; ++d) {
        float w = W[d * D + lane];          // coalesced across lanes
        float x = __shfl(nv, d, 64);        // broadcast neigh[d]
        acc = fmaf(x, w, acc);
    }
    out[node * D + lane] = acc;
}

extern "C" void kernel_launch(void* const* d_in, const int* in_sizes, int n_in,
                              void* d_out, int out_size, void* d_ws, size_t ws_size,
                              hipStream_t stream) {
    const float* feat   = (const float*)d_in[0];
    const float* gate_W = (const float*)d_in[1];
    const float* gate_b = (const float*)d_in[2];
    const int*   src    = (const int*)d_in[3];
    const int*   dst    = (const int*)d_in[4];
    const int*   ntype2 = (const int*)d_in[5];
    // d_in[6] = act_flag, no-op in this configuration

    float* out = (float*)d_out;            // doubles as the segment-sum accumulator
    float* deg = (float*)d_ws;             // [N_NODES] floats of scratch

    hipMemsetAsync(out, 0, sizeof(float) * N_NODES * D, stream);
    hipMemsetAsync(deg, 0, sizeof(float) * N_NODES, stream);

    {   // scatter features: 64M threads
        long long total = (long long)N_EDGES * D;
        int block = 256;
        int grid = (int)((total + block - 1) / block);
        scatter_feat<<<grid, block, 0, stream>>>(feat, src, dst, out);
    }
    {   // degrees: 1M threads
        int block = 256;
        int grid = (N_EDGES + block - 1) / block;
        scatter_deg<<<grid, block, 0, stream>>>(dst, deg);
    }
    {   // apply: one wave per node, 4 nodes per 256-thread block
        int block = 256;
        int nodes_per_block = block / 64;
        int grid = (N_NODES + nodes_per_block - 1) / nodes_per_block;
        apply_linear<<<grid, block, 0, stream>>>(gate_W, gate_b, ntype2, deg, out);
    }
}